// Round 1
// 747.300 us; speedup vs baseline: 1.1683x; 1.1683x over previous
//
#include <hip/hip_runtime.h>
#include <hip/hip_fp16.h>
#include <stdint.h>
#include <stddef.h>

#define NL   512                 // transform size
#define NF   257                 // number of filters (1 + 16*16)
#define NNE  (NL*NL)             // elements per plane
#define TWO_PI_OVER_N 0.012271846303085130f   // 2*pi/512

// ---------------- helpers ----------------
__device__ __forceinline__ unsigned short f2bf(float x) {   // fp32 -> bf16 RNE
  unsigned int u = __float_as_uint(x);
  u += 0x7fffu + ((u >> 16) & 1u);
  return (unsigned short)(u >> 16);
}

typedef __attribute__((ext_vector_type(8))) short bf16x8;
typedef __attribute__((ext_vector_type(4))) float f32x4;

// Bank swizzle for the in-place FFT arrays: XOR bits 5,6 into bits 3,4 AND
// bits 1,2. Bijective (bits 5,6 unchanged), preserves bit 0 adjacency and
// 2-element blocks. Makes all fused-radix-4 stage accesses <=2-way.
__device__ __forceinline__ int swz(int i) {
  return i ^ (((i >> 2) & 24) | ((i >> 4) & 6));
}

// ---------------- pass 1: row IFFTs (two rows per block) ----------------
// in[c] = x_hat[r,c] * psi[f,r,c]; 512-pt inverse DFT (sign +, unnormalized)
// along c, in-place DIF as 4 fused radix-4 stages + final radix-2 fused with
// the fp16 store -> bit-reversed c order (harmless: downstream stats are
// permutation invariant, consistent across filters). Twiddles are stage-major
// (stride-1 reads, conflict-free); data arrays are XOR-swizzled.
__global__ __launch_bounds__(256) void pass1_rows(const float* __restrict__ x,
                                                  const float* __restrict__ pr,
                                                  const float* __restrict__ pi,
                                                  __half2* __restrict__ W,
                                                  int f0) {
  __shared__ float Xr[2 * NL], Xi[2 * NL];
  __shared__ float4 twp[170];        // stage-major: (cosA, sinA, cosB, sinB)
  const int t    = threadIdx.x;
  const int half = t >> 7;           // which of the 2 rows
  const int p    = t & 127;          // lane within the row's 128 threads
  const int r    = blockIdx.x * 2 + half;
  const int fb   = blockIdx.y;
  const int f    = f0 + fb;
  const int base = half * NL;

  // stage-major twiddle fill: stages s=0..3 have hh = 128,32,8,2 entries at
  // offsets 0,128,160,168. angleA = k*2^(2s)*(2pi/512), angleB = 2*angleA.
  if (t < 170) {
    int s_  = (t < 128) ? 0 : (t < 160) ? 1 : (t < 168) ? 2 : 3;
    int off = (s_ == 0) ? 0 : (s_ == 1) ? 128 : (s_ == 2) ? 160 : 168;
    int k   = t - off;
    float ang = (float)(k << (2 * s_)) * TWO_PI_OVER_N;
    float sA, cA, sB, cB;
    __sincosf(ang, &sA, &cA);
    __sincosf(2.f * ang, &sB, &cB);
    twp[t] = make_float4(cA, sA, cB, sB);
  }

  // load + complex multiply (float4 vectorized, 16 B/lane)
  const size_t prow = ((size_t)f * NL + r) * NL;
  const float4* pr4 = (const float4*)(pr + prow);
  const float4* pi4 = (const float4*)(pi + prow);
  const float4* xr4 = (const float4*)(x + (size_t)r * (2 * NL));
  {
    float4 a  = pr4[p];
    float4 b  = pi4[p];
    float4 x0 = xr4[2 * p];          // complex c,c+1  (c = 4p)
    float4 x1 = xr4[2 * p + 1];      // complex c+2,c+3
    float v0r = x0.x * a.x - x0.y * b.x, v0i = x0.x * b.x + x0.y * a.x;
    float v1r = x0.z * a.y - x0.w * b.y, v1i = x0.z * b.y + x0.w * a.y;
    float v2r = x1.x * a.z - x1.y * b.z, v2i = x1.x * b.z + x1.y * a.z;
    float v3r = x1.z * a.w - x1.w * b.w, v3i = x1.z * b.w + x1.w * a.w;
    int s0i = base + swz(4 * p);      // covers logical 4p, 4p+1
    int s1i = base + swz(4 * p + 2);  // covers logical 4p+2, 4p+3
    *(float2*)&Xr[s0i] = make_float2(v0r, v1r);
    *(float2*)&Xr[s1i] = make_float2(v2r, v3r);
    *(float2*)&Xi[s0i] = make_float2(v0i, v1i);
    *(float2*)&Xi[s1i] = make_float2(v2i, v3i);
  }
  __syncthreads();

  // 4 fused radix-4 stages: levels (256,128),(64,32),(16,8),(4,2)
#pragma unroll
  for (int s_ = 0; s_ < 4; ++s_) {
    const int lh  = 8 - 2 * s_;                 // log2 of first level half-size*? (H = 2^lh)
    const int hh  = 1 << (lh - 1);              // 128,32,8,2
    const int off = (s_ == 0) ? 0 : (s_ == 1) ? 128 : (s_ == 2) ? 160 : 168;
    const int k   = p & (hh - 1);
    const int j0  = ((p >> (lh - 1)) << (lh + 1)) + k;
    const int i0  = base + swz(j0);
    const int i1  = base + swz(j0 + hh);
    const int i2  = base + swz(j0 + 2 * hh);
    const int i3  = base + swz(j0 + 3 * hh);
    float4 w = twp[off + k];                    // (cA,sA,cB,sB)
    float e0r = Xr[i0], e0i = Xi[i0], e2r = Xr[i2], e2i = Xi[i2];
    float e1r = Xr[i1], e1i = Xi[i1], e3r = Xr[i3], e3i = Xi[i3];
    // level A (pairs at distance 2hh): (e0,e2) tw^k, (e1,e3) tw^k * i
    float f0r = e0r + e2r, f0i = e0i + e2i;
    float f1r = e1r + e3r, f1i = e1i + e3i;
    float d2r = e0r - e2r, d2i = e0i - e2i;
    float d3r = e1r - e3r, d3i = e1i - e3i;
    float g2r = d2r * w.x - d2i * w.y, g2i = d2i * w.x + d2r * w.y;
    float t3r = d3r * w.x - d3i * w.y, t3i = d3i * w.x + d3r * w.y;
    float g3r = -t3i, g3i = t3r;                // * i  (inverse-sign transform)
    // level B (pairs at distance hh): (f0,f1) and (g2,g3), both tw^(2k)
    Xr[i0] = f0r + f1r;  Xi[i0] = f0i + f1i;
    float d0r = f0r - f1r, d0i = f0i - f1i;
    Xr[i1] = d0r * w.z - d0i * w.w;  Xi[i1] = d0i * w.z + d0r * w.w;
    Xr[i2] = g2r + g3r;  Xi[i2] = g2i + g3i;
    float d1r = g2r - g3r, d1i = g2i - g3i;
    Xr[i3] = d1r * w.z - d1i * w.w;  Xi[i3] = d1i * w.z + d1r * w.w;
    __syncthreads();
  }

  // final radix-2 (tw = 1) fused with fp16 store (8 B/lane, coalesced)
  __half2* Wrow = W + ((size_t)fb * NL + r) * NL;
#pragma unroll
  for (int u = 0; u < 2; ++u) {
    int q  = p + u * 128;                       // pair index 0..255
    int a0 = base + swz(2 * q);                 // swz(2q+1) == swz(2q)+1
    float2 rr = *(const float2*)&Xr[a0];
    float2 ri = *(const float2*)&Xi[a0];
    union { float2 fv; __half2 h[2]; } pk;
    pk.h[0] = __floats2half2_rn(rr.x + rr.y, ri.x + ri.y);
    pk.h[1] = __floats2half2_rn(rr.x - rr.y, ri.x - ri.y);
    ((float2*)Wrow)[q] = pk.fv;
  }
}

// ---------------- pass 2: column IFFTs, 16 columns per block ----------------
// Packed-fp16 in-LDS FFT: complex as __half2, column stride 513 (odd ->
// adjacent columns on disjoint bank parities). Fused radix-4 stages with
// stage-major twiddle tables (stride-1 / broadcast reads, conflict-free).
// Final radix-2 stage fused with the modulus (fp32) + bf16 store.
#define P2S 513   // half2 units per column in LDS
__global__ __launch_bounds__(512) void pass2_cols(const __half2* __restrict__ W,
                                                  unsigned short* __restrict__ m,
                                                  int f0) {
  __shared__ __half2 XX[16 * P2S];      // 32832 B
  __shared__ uint2 twAB[170];           // {(cA,cA), (-sA,sA)} stage-major
  __shared__ uint2 twCD[170];           // {(cB,cB), (-sB,sB)} stage-major
  const int t    = threadIdx.x;
  const int tile = blockIdx.x;          // 0..31
  const int fb   = blockIdx.y;
  const int f    = f0 + fb;
  const int c0   = tile * 16;

  if (t < 170) {
    int s_  = (t < 128) ? 0 : (t < 160) ? 1 : (t < 168) ? 2 : 3;
    int off = (s_ == 0) ? 0 : (s_ == 1) ? 128 : (s_ == 2) ? 160 : 168;
    int k   = t - off;
    float ang = (float)(k << (2 * s_)) * TWO_PI_OVER_N;
    float sn, cs;
    __sincosf(ang, &sn, &cs);
    __half2 a = __floats2half2_rn(cs, cs), b = __floats2half2_rn(-sn, sn);
    twAB[t] = make_uint2(*(unsigned int*)&a, *(unsigned int*)&b);
    __sincosf(2.f * ang, &sn, &cs);
    a = __floats2half2_rn(cs, cs); b = __floats2half2_rn(-sn, sn);
    twCD[t] = make_uint2(*(unsigned int*)&a, *(unsigned int*)&b);
  }

  // load 512x16 fp16-complex tile (64-B row segments, coalesced)
  const uint4* Wp4 = (const uint4*)(W + (size_t)fb * NNE);
#pragma unroll
  for (int it = 0; it < 4; ++it) {
    int sl = it * 512 + t;
    int r = sl >> 2, g = sl & 3;
    uint4 v = Wp4[r * 128 + (c0 >> 2) + g];
    int cl = g * 4;
    XX[(cl + 0) * P2S + r] = *(__half2*)&v.x;
    XX[(cl + 1) * P2S + r] = *(__half2*)&v.y;
    XX[(cl + 2) * P2S + r] = *(__half2*)&v.z;
    XX[(cl + 3) * P2S + r] = *(__half2*)&v.w;
  }
  __syncthreads();

  const int col = t >> 5;               // 16 columns x 32 threads
  const int b0  = t & 31;
  const int cb  = col * P2S;
  const __half2 mI = __floats2half2_rn(-1.f, 1.f);   // multiply-by-i helper

  // fused radix-4: stages (8,7),(6,5),(4,3),(2,1)
#pragma unroll
  for (int s_ = 0; s_ < 4; ++s_) {
    const int lh  = 8 - 2 * s_;
    const int hh  = 1 << (lh - 1);
    const int off = (s_ == 0) ? 0 : (s_ == 1) ? 128 : (s_ == 2) ? 160 : 168;
#pragma unroll
    for (int q = 0; q < 4; ++q) {
      int p  = b0 + q * 32;             // 128 fused slots per column
      int k  = p & (hh - 1);
      int B  = (p >> (lh - 1)) << (lh + 1);
      int i0 = cb + B + k, i1 = i0 + hh, i2 = i0 + 2 * hh, i3 = i0 + 3 * hh;
      __half2 e0 = XX[i0], e1 = XX[i1], e2 = XX[i2], e3 = XX[i3];
      uint2 vA = twAB[off + k];
      uint2 vB = twCD[off + k];
      __half2 aA = *(__half2*)&vA.x, bA = *(__half2*)&vA.y;
      __half2 aB = *(__half2*)&vB.x, bB = *(__half2*)&vB.y;
      // level 1 (stage h): pairs (e0,e2) tw^k, (e1,e3) tw^(k+hh) = i*tw^k
      __half2 f0v = __hadd2(e0, e2);
      __half2 f1v = __hadd2(e1, e3);
      __half2 d02 = __hsub2(e0, e2);
      __half2 d13 = __hsub2(e1, e3);
      __half2 f2v = __hfma2(d02, aA, __hmul2(__lowhigh2highlow(d02), bA));
      __half2 t3  = __hfma2(d13, aA, __hmul2(__lowhigh2highlow(d13), bA));
      __half2 f3v = __hmul2(__lowhigh2highlow(t3), mI);   // * i
      // level 2 (stage h/2): pairs (f0,f1) and (f2,f3), both tw^(2k)
      XX[i0] = __hadd2(f0v, f1v);
      __half2 d01 = __hsub2(f0v, f1v);
      XX[i1] = __hfma2(d01, aB, __hmul2(__lowhigh2highlow(d01), bB));
      XX[i2] = __hadd2(f2v, f3v);
      __half2 d23 = __hsub2(f2v, f3v);
      XX[i3] = __hfma2(d23, aB, __hmul2(__lowhigh2highlow(d23), bB));
    }
    __syncthreads();
  }

  // final radix-2 stage (tw = 1) fused with modulus + bf16 store
  const float inv = 1.0f / (float)NNE;
  unsigned int* mp = (unsigned int*)(m + (size_t)f * NNE + (size_t)(c0 + col) * NL);
#pragma unroll
  for (int u = 0; u < 8; ++u) {
    int p = b0 + u * 32;                // 256 pairs per column
    __half2 a = XX[cb + 2 * p], b = XX[cb + 2 * p + 1];
    float2 af = __half22float2(a), bf = __half22float2(b);
    float r0 = (af.x + bf.x) * inv, s0 = (af.y + bf.y) * inv;
    float r1 = (af.x - bf.x) * inv, s1 = (af.y - bf.y) * inv;
    float m0 = sqrtf(r0 * r0 + s0 * s0 + 1e-8f);
    float m1 = sqrtf(r1 * r1 + s1 * s1 + 1e-8f);
    mp[p] = (unsigned int)f2bf(m0) | ((unsigned int)f2bf(m1) << 16);
  }
}

// ---------------- Gram kernel: 16x16 plane-Gram per group via MFMA ----------
// groups 0..15  : scale j  -> planes p[k=0..15, j]   (E2 diag + C1 pairs)
// groups 16..31 : orient k -> planes p[k, j=0..15]   (C2 pairs)
// A-frag == B-frag (same lane data) gives C = P*P^T directly.
__global__ __launch_bounds__(256) void gram_kernel(const unsigned short* __restrict__ m,
                                                   float* __restrict__ G) {
  const int chunk = blockIdx.x;     // 0..31
  const int g     = blockIdx.y;     // 0..31
  const int wave  = threadIdx.x >> 6;
  const int lane  = threadIdx.x & 63;
  const int mrow  = lane & 15;
  const int quad  = lane >> 4;
  const int pidx  = (g < 16) ? (1 + mrow * 16 + g) : (1 + (g - 16) * 16 + mrow);
  const unsigned short* plane = m + (size_t)pidx * NNE;
  const int base0 = chunk * 8192 + wave * 2048 + quad * 8;

  f32x4 acc = {0.f, 0.f, 0.f, 0.f};
#pragma unroll 4
  for (int it = 0; it < 64; ++it) {
    bf16x8 frag = *(const bf16x8*)(plane + base0 + it * 32);
    acc = __builtin_amdgcn_mfma_f32_16x16x32_bf16(frag, frag, acc, 0, 0, 0);
  }
  const int colo = lane & 15;
  const int row0 = quad * 4;
#pragma unroll
  for (int rr = 0; rr < 4; ++rr)
    atomicAdd(&G[g * 256 + (row0 + rr) * 16 + colo], acc[rr]);
}

// ---------------- Ea / s0 kernel: dot(plane_f, plane_a) ----------------
__global__ __launch_bounds__(256) void ea_kernel(const unsigned short* __restrict__ m,
                                                 float* __restrict__ EA) {
  const int f = blockIdx.x, chunk = blockIdx.y, t = threadIdx.x;
  const unsigned short* p = m + (size_t)f * NNE + chunk * 16384;
  const unsigned short* a = m + chunk * 16384;
  float acc = 0.f;
  for (int it = 0; it < 8; ++it) {
    int off = (it * 256 + t) * 8;
    uint4 up = *(const uint4*)(p + off);
    uint4 ua = *(const uint4*)(a + off);
    const unsigned int pw[4] = {up.x, up.y, up.z, up.w};
    const unsigned int aw[4] = {ua.x, ua.y, ua.z, ua.w};
#pragma unroll
    for (int q = 0; q < 4; ++q) {
      acc += __uint_as_float(pw[q] << 16) * __uint_as_float(aw[q] << 16);
      acc += __uint_as_float(pw[q] & 0xffff0000u) * __uint_as_float(aw[q] & 0xffff0000u);
    }
  }
  __shared__ float red[256];
  red[t] = acc; __syncthreads();
  for (int w = 128; w > 0; w >>= 1) { if (t < w) red[t] += red[t + w]; __syncthreads(); }
  if (t == 0) atomicAdd(&EA[f], red[0]);
}

// ---------------- zero accumulators ----------------
__global__ void zero_acc(float* g) {
  int i = blockIdx.x * 256 + threadIdx.x;
  if (i < 8449) g[i] = 0.f;        // 32*256 Gram + 257 EA floats
}

// ---------------- assemble output in reference ordering ----------------
__global__ __launch_bounds__(256) void assemble_kernel(const float* __restrict__ G,
                                                       const float* __restrict__ EA,
                                                       float* __restrict__ out) {
  const float inv = 1.0f / (float)NNE;
  const int t = threadIdx.x;
  const int i = t >> 4, j = t & 15;
  int base = 1;
  for (int c = 0; c < t; ++c) {
    int ci = c >> 4, cj = c & 15;
    base += 2 + (15 - ci) + (15 - cj);
  }
  if (t == 0) out[0] = EA[0] * inv;                        // s0 = mean(a^2)
  float* o = out + base;
  int n = 0;
  o[n++] = G[j * 256 + i * 16 + i] * inv;                  // E2[i,j]
  o[n++] = EA[1 + i * 16 + j] * inv;                       // Ea[i,j]
  for (int l = i + 1; l < 16; ++l)                         // C1[i, l, j]
    o[n++] = G[j * 256 + i * 16 + l] * inv;
  for (int l = j + 1; l < 16; ++l)                         // C2[i, j, l]
    o[n++] = G[(16 + i) * 256 + j * 16 + l] * inv;
}

// ---------------- launcher ----------------
extern "C" void kernel_launch(void* const* d_in, const int* in_sizes, int n_in,
                              void* d_out, int out_size, void* d_ws, size_t ws_size,
                              hipStream_t stream) {
  const float* x  = (const float*)d_in[0];   // [512,512,2]
  const float* pr = (const float*)d_in[1];   // [257,512,512]
  const float* pi = (const float*)d_in[2];   // [257,512,512]
  float* out = (float*)d_out;
  char* ws = (char*)d_ws;

  // ws layout: m planes (bf16) | Gram acc | EA acc | W batch buffer (fp16 complex)
  unsigned short* m = (unsigned short*)ws;                       // 257*512*512*2 B
  const size_t g_off = (size_t)NF * NNE * 2;                     // 134,742,016
  float* G  = (float*)(ws + g_off);                              // 32*256 fp32
  float* EA = (float*)(ws + g_off + 32768);                      // 257 fp32
  const size_t w_off = g_off + 33808;                            // 16-aligned
  __half2* W = (__half2*)(ws + w_off);

  size_t avail = ws_size > w_off ? ws_size - w_off : 0;
  int BF = (int)(avail / ((size_t)NNE * 4));                     // filters per batch
  if (BF < 1)  BF = 1;
  if (BF > NF) BF = NF;

  zero_acc<<<34, 256, 0, stream>>>(G);

  for (int f0 = 0; f0 < NF; f0 += BF) {
    int bf = NF - f0 < BF ? NF - f0 : BF;
    pass1_rows<<<dim3(256, bf), 256, 0, stream>>>(x, pr, pi, W, f0);
    pass2_cols<<<dim3(32, bf), 512, 0, stream>>>(W, m, f0);
  }

  gram_kernel<<<dim3(32, 32), 256, 0, stream>>>(m, G);
  ea_kernel<<<dim3(NF, 16), 256, 0, stream>>>(m, EA);
  assemble_kernel<<<1, 256, 0, stream>>>(G, EA, out);
}